// Round 6
// baseline (3858.623 us; speedup 1.0000x reference)
//
#include <hip/hip_runtime.h>
#include <hip/hip_fp16.h>
#include <math.h>

#define B_ 32
#define S_ 1024
#define D_ 768
#define L_ 12
#define SD 786432LL      // S_*D_ halves per batch
#define SS 1048576LL     // S_*S_ halves per batch
#define DD 589824LL      // D_*D_
#define LDL 1769472LL    // 3*DD halves per layer of Wcat (2304 x 768)

typedef _Float16 half8 __attribute__((ext_vector_type(8)));
typedef float f32x4 __attribute__((ext_vector_type(4)));
typedef unsigned short u16;

// ===========================================================================
// Epilogue LDS-bounce layout (per 64x64 wave quadrant, half index):
//   H(lr, lc) = lr*64 + (((lc>>4) ^ (lr&3))<<4) + (lc&15)
// 32B superchunks XOR-permuted by lr&3: b64 writes land 4-way worst case
// (1.58x, vs 8-way/2.94x before), readback of 8 consecutive cols is one
// b128 at a 16B-aligned address.
// MFMA operand order is SWAPPED (mfma(bf, af, acc)) so reg i = consecutive
// n-columns per lane -> 4 halves pack into one ds_write_b64.
// ===========================================================================

// ---------------------------------------------------------------------------
// Fused QKV projection, m-slab XCD-swizzled (XCD x owns contiguous m-tiles;
// per-XCD L2 working set = rolling A slab + 3.4 MB Wcat).
// C_cat = A(M x 768) . Wcat(2304 x 768)^T; epilogue region-split:
//   n_cat in [0,768) -> CQ, [768,1536) -> CK (*lk), [1536,..) -> CVt transposed.
// v = (acc + aBias*biasC[n]) * scaleC[n], stored fp16.
// ---------------------------------------------------------------------------
__global__ __launch_bounds__(256, 2)
void gemm_qkv_k(const __half* __restrict__ A, const __half* __restrict__ Wt,
                const float* __restrict__ biasC, const float* __restrict__ scaleC,
                float aBias,
                __half* __restrict__ CQ, __half* __restrict__ CK, __half* __restrict__ CVt,
                int nBase, int tilesX, int mPerXcd)
{
    __shared__ __align__(16) u16 smem[16384];
    const int K = 768;

    const int flat = blockIdx.x;
    const int xcd = flat & 7;
    const int jj = flat >> 3;
    const int mLocal = jj / tilesX;
    const int nxI = jj - mLocal * tilesX;
    const int n0 = nxI * 128;
    const int m0 = (xcd * mPerXcd + mLocal) * 128;

    const int t = threadIdx.x;
    const int l = t & 63, w = t >> 6;
    const int quad = l >> 4;
    const int wm = (w & 1) * 64, wn = (w >> 1) * 64;

    const int u0 = t, u1 = t + 256;
    const int r0 = u0 >> 2, c0 = (u0 & 3) ^ (r0 & 3);
    const int r1 = u1 >> 2, c1 = (u1 & 3) ^ (r1 & 3);
    const __half* gA0 = A + (long long)(m0 + r0) * K + c0 * 8;
    const __half* gA1 = A + (long long)(m0 + r1) * K + c1 * 8;
    const __half* gB0 = Wt + (long long)(n0 + r0) * K + c0 * 8;
    const __half* gB1 = Wt + (long long)(n0 + r1) * K + c1 * 8;
    u16* lA0 = &smem[u0 * 8];
    u16* lA1 = &smem[u1 * 8];
    u16* lB0 = &smem[4096 + u0 * 8];
    u16* lB1 = &smem[4096 + u1 * 8];

    int aoff[4], boff[4];
    const int kc = l >> 4;
    #pragma unroll
    for (int mt = 0; mt < 4; ++mt) {
        int rr = wm + mt * 16 + (l & 15);
        aoff[mt] = (rr * 4 + (kc ^ (rr & 3))) * 8;
        int rb = wn + mt * 16 + (l & 15);
        boff[mt] = (rb * 4 + (kc ^ (rb & 3))) * 8;
    }

    f32x4 acc[4][4];
    #pragma unroll
    for (int i = 0; i < 4; ++i)
        #pragma unroll
        for (int j = 0; j < 4; ++j)
            acc[i][j] = (f32x4){0.f, 0.f, 0.f, 0.f};

    for (int k0 = 0; k0 < K; k0 += 32) {
        __builtin_amdgcn_global_load_lds((const __attribute__((address_space(1))) void*)(gA0 + k0),
                                         (__attribute__((address_space(3))) void*)lA0, 16, 0, 0);
        __builtin_amdgcn_global_load_lds((const __attribute__((address_space(1))) void*)(gA1 + k0),
                                         (__attribute__((address_space(3))) void*)lA1, 16, 0, 0);
        __builtin_amdgcn_global_load_lds((const __attribute__((address_space(1))) void*)(gB0 + k0),
                                         (__attribute__((address_space(3))) void*)lB0, 16, 0, 0);
        __builtin_amdgcn_global_load_lds((const __attribute__((address_space(1))) void*)(gB1 + k0),
                                         (__attribute__((address_space(3))) void*)lB1, 16, 0, 0);
        __syncthreads();

        half8 af[4], bf[4];
        #pragma unroll
        for (int mt = 0; mt < 4; ++mt) af[mt] = *(const half8*)(const void*)&smem[aoff[mt]];
        #pragma unroll
        for (int nt = 0; nt < 4; ++nt) bf[nt] = *(const half8*)(const void*)&smem[4096 + boff[nt]];

        #pragma unroll
        for (int nt = 0; nt < 4; ++nt)
            #pragma unroll
            for (int mt = 0; mt < 4; ++mt)
                acc[mt][nt] = __builtin_amdgcn_mfma_f32_16x16x32_f16(bf[nt], af[mt], acc[mt][nt], 0, 0, 0);
        __syncthreads();
    }

    const int nCat0 = n0 + nBase;
    const int region = nCat0 / 768;
    const int colBase = nCat0 - region * 768;

    const int qbase = w * 4096;
    #pragma unroll
    for (int nt = 0; nt < 4; ++nt) {
        float badd[4], bmul[4];
        #pragma unroll
        for (int i = 0; i < 4; ++i) {
            int gn = nCat0 + wn + nt * 16 + quad * 4 + i;
            badd[i] = aBias * biasC[gn];
            bmul[i] = scaleC[gn];
        }
        #pragma unroll
        for (int mt = 0; mt < 4; ++mt) {
            int lr = mt * 16 + (l & 15);
            float v0 = (acc[mt][nt][0] + badd[0]) * bmul[0];
            float v1 = (acc[mt][nt][1] + badd[1]) * bmul[1];
            float v2 = (acc[mt][nt][2] + badd[2]) * bmul[2];
            float v3 = (acc[mt][nt][3] + badd[3]) * bmul[3];
            __half2 h01 = __floats2half2_rn(v0, v1);
            __half2 h23 = __floats2half2_rn(v2, v3);
            uint2 pk;
            pk.x = *(const unsigned int*)&h01;
            pk.y = *(const unsigned int*)&h23;
            int pos = qbase + lr * 64 + (((nt ^ (lr & 3))) << 4) + (quad << 2);
            *(uint2*)(void*)&smem[pos] = pk;
        }
    }
    __syncthreads();

    if (region < 2) {
        __half* Creg = region ? CK : CQ;
        #pragma unroll
        for (int p = 0; p < 8; ++p) {
            int u = t + p * 256;
            int R = u >> 4, cc = u & 15;
            int qb = ((R >> 6) + ((cc >> 3) << 1)) * 4096;
            int lr = R & 63, hc = cc & 7;
            int pos = qb + lr * 64 + (((hc >> 1) ^ (lr & 3)) << 4) + ((hc & 1) << 3);
            half8 val = *(const half8*)(const void*)&smem[pos];
            *(half8*)(void*)&Creg[(long long)(m0 + R) * 768 + colBase + cc * 8] = val;
        }
    } else {
        #pragma unroll
        for (int p = 0; p < 8; ++p) {
            int u = t + p * 256;
            int Crow = u >> 4, mcc = u & 15;
            __align__(16) u16 tmp[8];
            int lc = Crow & 63;
            #pragma unroll
            for (int j = 0; j < 8; ++j) {
                int m = mcc * 8 + j;
                int qb = ((m >> 6) + ((Crow >> 6) << 1)) * 4096;
                int lr = m & 63;
                int pos = qb + lr * 64 + (((lc >> 4) ^ (lr & 3)) << 4) + (lc & 15);
                tmp[j] = smem[pos];
            }
            long long b = m0 >> 10;
            __half* dst = CVt + b * SD + (long long)(colBase + Crow) * 1024 + (m0 & 1023) + mcc * 8;
            *(half8*)(void*)dst = *(const half8*)(const void*)tmp;
        }
    }
}

// ===========================================================================
// Attention GEMM: C = f(A[1024 x K] . B[N x K]^T), per-batch.
// MODE 1 (QK^T): v = exp(acc*aAcc) -> fp16 P + per-(row,coltile) partial
//                sums to rsp (no-max softmax; scores bounded small here).
// MODE 2 (PV):   v = acc * aAcc / rowsum, rowsum reduced inline from rsp.
// SWIZ=1: batch b pinned to XCD b/bpx, matching the QKV m-slab mapping.
// ===========================================================================
template<int SWIZ, int MODE>
__global__ __launch_bounds__(256, 2)
void gemm_att_k(const __half* __restrict__ A, const __half* __restrict__ B,
                float aAcc, __half* __restrict__ C, int K, int ldc,
                long long sA, long long sB, long long sC,
                int tilesX, int tilesPB, int bpx, float* __restrict__ rsp)
{
    __shared__ __align__(16) u16 smem[16384];
    __shared__ float sums[128 * 17];

    int nxI, ny;
    long long bz;
    if (SWIZ) {
        int flat = blockIdx.x;
        int xcd = flat & 7;
        int j = flat >> 3;
        int bLocal = j / tilesPB;
        int tt = j - bLocal * tilesPB;
        bz = (long long)(xcd * bpx + bLocal);
        ny = tt / tilesX;
        nxI = tt - ny * tilesX;
    } else {
        nxI = blockIdx.x; ny = blockIdx.y; bz = blockIdx.z;
    }

    const int t = threadIdx.x;
    const int l = t & 63, w = t >> 6;
    const int quad = l >> 4;
    const int n0 = nxI * 128;
    const int m0 = ny * 128;
    A += bz * sA; B += bz * sB; C += bz * sC;

    const int wm = (w & 1) * 64, wn = (w >> 1) * 64;

    const int u0 = t, u1 = t + 256;
    const int r0 = u0 >> 2, c0 = (u0 & 3) ^ (r0 & 3);
    const int r1 = u1 >> 2, c1 = (u1 & 3) ^ (r1 & 3);
    const __half* gA0 = A + (long long)(m0 + r0) * K + c0 * 8;
    const __half* gA1 = A + (long long)(m0 + r1) * K + c1 * 8;
    const __half* gB0 = B + (long long)(n0 + r0) * K + c0 * 8;
    const __half* gB1 = B + (long long)(n0 + r1) * K + c1 * 8;
    u16* lA0 = &smem[u0 * 8];
    u16* lA1 = &smem[u1 * 8];
    u16* lB0 = &smem[4096 + u0 * 8];
    u16* lB1 = &smem[4096 + u1 * 8];

    int aoff[4], boff[4];
    const int kc = l >> 4;
    #pragma unroll
    for (int mt = 0; mt < 4; ++mt) {
        int rr = wm + mt * 16 + (l & 15);
        aoff[mt] = (rr * 4 + (kc ^ (rr & 3))) * 8;
        int rb = wn + mt * 16 + (l & 15);
        boff[mt] = (rb * 4 + (kc ^ (rb & 3))) * 8;
    }

    f32x4 acc[4][4];
    #pragma unroll
    for (int i = 0; i < 4; ++i)
        #pragma unroll
        for (int j = 0; j < 4; ++j)
            acc[i][j] = (f32x4){0.f, 0.f, 0.f, 0.f};

    for (int k0 = 0; k0 < K; k0 += 32) {
        __builtin_amdgcn_global_load_lds((const __attribute__((address_space(1))) void*)(gA0 + k0),
                                         (__attribute__((address_space(3))) void*)lA0, 16, 0, 0);
        __builtin_amdgcn_global_load_lds((const __attribute__((address_space(1))) void*)(gA1 + k0),
                                         (__attribute__((address_space(3))) void*)lA1, 16, 0, 0);
        __builtin_amdgcn_global_load_lds((const __attribute__((address_space(1))) void*)(gB0 + k0),
                                         (__attribute__((address_space(3))) void*)lB0, 16, 0, 0);
        __builtin_amdgcn_global_load_lds((const __attribute__((address_space(1))) void*)(gB1 + k0),
                                         (__attribute__((address_space(3))) void*)lB1, 16, 0, 0);
        __syncthreads();

        half8 af[4], bf[4];
        #pragma unroll
        for (int mt = 0; mt < 4; ++mt) af[mt] = *(const half8*)(const void*)&smem[aoff[mt]];
        #pragma unroll
        for (int nt = 0; nt < 4; ++nt) bf[nt] = *(const half8*)(const void*)&smem[4096 + boff[nt]];

        #pragma unroll
        for (int nt = 0; nt < 4; ++nt)
            #pragma unroll
            for (int mt = 0; mt < 4; ++mt)
                acc[mt][nt] = __builtin_amdgcn_mfma_f32_16x16x32_f16(bf[nt], af[mt], acc[mt][nt], 0, 0, 0);
        __syncthreads();
    }

    const int qbase = w * 4096;
    #pragma unroll
    for (int mt = 0; mt < 4; ++mt) {
        int lr = mt * 16 + (l & 15);
        float scl = aAcc;
        if (MODE == 2) {
            const float* pr = rsp + bz * 8192 + (long long)(m0 + wm + lr) * 8;
            float s = ((pr[0] + pr[1]) + (pr[2] + pr[3])) + ((pr[4] + pr[5]) + (pr[6] + pr[7]));
            scl = aAcc / s;
        }
        #pragma unroll
        for (int nt = 0; nt < 4; ++nt) {
            float v0, v1, v2, v3;
            if (MODE == 1) {
                v0 = __expf(acc[mt][nt][0] * aAcc);
                v1 = __expf(acc[mt][nt][1] * aAcc);
                v2 = __expf(acc[mt][nt][2] * aAcc);
                v3 = __expf(acc[mt][nt][3] * aAcc);
            } else {
                v0 = acc[mt][nt][0] * scl;
                v1 = acc[mt][nt][1] * scl;
                v2 = acc[mt][nt][2] * scl;
                v3 = acc[mt][nt][3] * scl;
            }
            __half2 h01 = __floats2half2_rn(v0, v1);
            __half2 h23 = __floats2half2_rn(v2, v3);
            uint2 pk;
            pk.x = *(const unsigned int*)&h01;
            pk.y = *(const unsigned int*)&h23;
            int pos = qbase + lr * 64 + (((nt ^ (lr & 3))) << 4) + (quad << 2);
            *(uint2*)(void*)&smem[pos] = pk;
        }
    }
    __syncthreads();

    #pragma unroll
    for (int p = 0; p < 8; ++p) {
        int u = t + p * 256;
        int R = u >> 4, cc = u & 15;
        int qb = ((R >> 6) + ((cc >> 3) << 1)) * 4096;
        int lr = R & 63, hc = cc & 7;
        int pos = qb + lr * 64 + (((hc >> 1) ^ (lr & 3)) << 4) + ((hc & 1) << 3);
        half8 val = *(const half8*)(const void*)&smem[pos];
        *(half8*)(void*)&C[(long long)(m0 + R) * ldc + n0 + cc * 8] = val;
        if (MODE == 1) {
            float s8 = 0.f;
            #pragma unroll
            for (int j = 0; j < 8; ++j) s8 += (float)val[j];
            sums[R * 17 + cc] = s8;
        }
    }
    if (MODE == 1) {
        __syncthreads();
        if (t < 128) {
            float s = 0.f;
            #pragma unroll
            for (int c = 0; c < 16; ++c) s += sums[t * 17 + c];
            rsp[bz * 8192 + (long long)(m0 + t) * 8 + nxI] = s;
        }
    }
}

// ---------------------------------------------------------------------------
__global__ __launch_bounds__(256)
void cvt32to16_k(const float* __restrict__ X, __half* __restrict__ Y)
{
    long long i = ((long long)blockIdx.x * 256 + threadIdx.x) * 4;
    float4 v = *(const float4*)&X[i];
    *(__half2*)&Y[i]     = __floats2half2_rn(v.x, v.y);
    *(__half2*)&Y[i + 2] = __floats2half2_rn(v.z, v.w);
}

// W[l][k][n] fp32 -> Wcat[l][rowOff + n][k] fp16
__global__ __launch_bounds__(256)
void wtrans_k(const float* __restrict__ W, __half* __restrict__ Wt,
              long long ldL, int rowOff)
{
    __shared__ float Ls[64][65];
    const int lyr = blockIdx.z;
    const int k0 = blockIdx.y * 64, n0 = blockIdx.x * 64;
    const float* src = W + (long long)lyr * DD;
    __half* dst = Wt + (long long)lyr * ldL;
    const int t = threadIdx.x;
    #pragma unroll
    for (int p = 0; p < 4; ++p) {
        int u = t + p * 256;
        int r = u >> 4, c4 = (u & 15) * 4;
        float4 v = *(const float4*)&src[(long long)(k0 + r) * D_ + n0 + c4];
        Ls[r][c4] = v.x; Ls[r][c4 + 1] = v.y; Ls[r][c4 + 2] = v.z; Ls[r][c4 + 3] = v.w;
    }
    __syncthreads();
    #pragma unroll
    for (int p = 0; p < 2; ++p) {
        int u = t + p * 256;
        int n = u >> 3, kc8 = (u & 7) * 8;
        __align__(16) u16 tmp[8];
        #pragma unroll
        for (int j = 0; j < 8; ++j) {
            _Float16 h = (_Float16)Ls[kc8 + j][n];
            tmp[j] = *(const u16*)&h;
        }
        *(half8*)(void*)&dst[(long long)(rowOff + n0 + n) * D_ + k0 + kc8] =
            *(const half8*)(const void*)tmp;
    }
}

// build concatenated bias/scale: [l][2304]: Q: (bq, 1) K: (bk, lk) V: (bv, lv)
__global__ __launch_bounds__(256)
void bscat_k(const float* __restrict__ bq, const float* __restrict__ bk,
             const float* __restrict__ bv, const float* __restrict__ lk,
             const float* __restrict__ lv, float* __restrict__ bsb,
             float* __restrict__ bss)
{
    int i = blockIdx.x * 256 + threadIdx.x;
    if (i >= L_ * 2304) return;
    int l = i / 2304, p = i - l * 2304;
    int r = p / 768, c = p - r * 768;
    float b, s;
    if (r == 0)      { b = bq[l * 768 + c]; s = 1.f; }
    else if (r == 1) { b = bk[l * 768 + c]; s = lk[l * 768 + c]; }
    else             { b = bv[l * 768 + c]; s = lv[l * 768 + c]; }
    bsb[i] = b; bss[i] = s;
}

// ---------------- layer-12 row-0 shortcut (fp32) ----------------
__global__ __launch_bounds__(256)
void q0_k(const __half* __restrict__ H16, const __half* __restrict__ Wcat,
          const float* __restrict__ bq, float* __restrict__ q0f, float sig)
{
    const int b = blockIdx.x;
    const int n = blockIdx.y * 256 + threadIdx.x;
    const int t = threadIdx.x;
    __shared__ __half hrow[768];
    const __half* h = H16 + (long long)b * SD;
    hrow[t] = h[t]; hrow[t + 256] = h[t + 256]; hrow[t + 512] = h[t + 512];
    __syncthreads();
    const __half* wr = Wcat + 11LL * LDL + (long long)n * 768;
    float acc = 0.f;
    for (int k = 0; k < 768; ++k) acc += (float)hrow[k] * (float)wr[k];
    q0f[b * 768 + n] = acc + sig * bq[11 * 768 + n];
}

__global__ __launch_bounds__(256)
void s0_k(const float* __restrict__ q0f, const __half* __restrict__ K16,
          float* __restrict__ s0f, int b0, float aQK)
{
    const int z = blockIdx.x;
    const int b = b0 + z;
    const int s = blockIdx.y * 256 + threadIdx.x;
    const int t = threadIdx.x;
    __shared__ float qrow[768];
    qrow[t] = q0f[b * 768 + t];
    qrow[t + 256] = q0f[b * 768 + t + 256];
    qrow[t + 512] = q0f[b * 768 + t + 512];
    __syncthreads();
    const __half* kr = K16 + (long long)z * SD + (long long)s * 768;
    float acc = 0.f;
    for (int k = 0; k < 768; ++k) acc += qrow[k] * (float)kr[k];
    s0f[b * 1024 + s] = acc * aQK;
}

__global__ __launch_bounds__(256)
void sm0_k(float* __restrict__ s0f, int b0)
{
    float* p = s0f + (long long)(b0 + blockIdx.x) * 1024;
    const int t = threadIdx.x;
    float v[4];
    float mx = -1e30f;
    #pragma unroll
    for (int j = 0; j < 4; ++j) { v[j] = p[t + 256 * j]; mx = fmaxf(mx, v[j]); }
    __shared__ float red[256];
    red[t] = mx; __syncthreads();
    for (int s = 128; s > 0; s >>= 1) { if (t < s) red[t] = fmaxf(red[t], red[t + s]); __syncthreads(); }
    mx = red[0];
    __syncthreads();
    float sum = 0.f;
    #pragma unroll
    for (int j = 0; j < 4; ++j) { v[j] = __expf(v[j] - mx); sum += v[j]; }
    red[t] = sum; __syncthreads();
    for (int s = 128; s > 0; s >>= 1) { if (t < s) red[t] += red[t + s]; __syncthreads(); }
    const float inv = 1.0f / red[0];
    __syncthreads();
    #pragma unroll
    for (int j = 0; j < 4; ++j) p[t + 256 * j] = v[j] * inv;
}

__global__ __launch_bounds__(256)
void o0_k(const float* __restrict__ p0f, const __half* __restrict__ Vt16,
          float* __restrict__ o0f, int b0, float invSig)
{
    const int z = blockIdx.x;
    const int b = b0 + z;
    const int d = blockIdx.y * 256 + threadIdx.x;
    const int t = threadIdx.x;
    __shared__ float prow[1024];
    #pragma unroll
    for (int j = 0; j < 4; ++j) prow[t + 256 * j] = p0f[b * 1024 + t + 256 * j];
    __syncthreads();
    const __half* vr = Vt16 + (long long)z * SD + (long long)d * 1024;
    float acc = 0.f;
    for (int s = 0; s < 1024; ++s) acc += prow[s] * (float)vr[s];
    o0f[b * 768 + d] = acc * invSig;
}

__global__ __launch_bounds__(256)
void headf_k(const float* __restrict__ o0f, const float* __restrict__ Wh,
             const float* __restrict__ bh, float* __restrict__ out)
{
    const int b = blockIdx.x;
    const int t = threadIdx.x;
    float s = 0.f;
    for (int d = t; d < 768; d += 256) s += o0f[b * 768 + d] * Wh[d];
    __shared__ float red[256];
    red[t] = s; __syncthreads();
    for (int k = 128; k > 0; k >>= 1) { if (t < k) red[t] += red[t + k]; __syncthreads(); }
    if (t == 0) out[b] = red[0] + bh[0];
}

// ---------------------------------------------------------------------------
extern "C" void kernel_launch(void* const* d_in, const int* in_sizes, int n_in,
                              void* d_out, int out_size, void* d_ws, size_t ws_size,
                              hipStream_t stream)
{
    const float* hs = (const float*)d_in[0];
    const float* Wq = (const float*)d_in[1];
    const float* bq = (const float*)d_in[2];
    const float* Wk = (const float*)d_in[3];
    const float* bk = (const float*)d_in[4];
    const float* Wv = (const float*)d_in[5];
    const float* bv = (const float*)d_in[6];
    const float* lk = (const float*)d_in[7];
    const float* lv = (const float*)d_in[8];
    const float* Wh = (const float*)d_in[9];
    const float* bh = (const float*)d_in[10];
    float* outp = (float*)d_out;

    // ---- workspace layout ----
    __half* H16  = (__half*)d_ws;                    // 32*SD halves
    __half* Wcat = H16 + (long long)B_ * SD;         // 12*LDL halves
    float*  bsb  = (float*)(Wcat + 12LL * LDL);      // 12*2304
    float*  bss  = bsb + 12 * 2304;
    float*  q0f  = bss + 12 * 2304;                  // 32*768
    float*  s0f  = q0f + 32 * 768;                   // 32*1024
    float*  o0f  = s0f + 32 * 1024;                  // 32*768
    float*  rsp  = o0f + 32 * 768;                   // 32*1024*8 partial rowsums
    __half* Q16  = (__half*)(rsp + 32LL * 8192);

    const size_t baseBytes = (size_t)((char*)Q16 - (char*)d_ws);
    const size_t perG = ((size_t)(3 * SD) + (size_t)SS) * 2;   // ~6.8 MB
    long long avail = (long long)ws_size - (long long)baseBytes;
    int G = (avail > 0) ? (int)(avail / perG) : 1;
    if (G >= 32) G = 32; else if (G >= 16) G = 16; else if (G >= 8) G = 8;
    if (G < 1) G = 1;
    __half* K16  = Q16 + (long long)G * SD;
    __half* Vt16 = K16 + (long long)G * SD;
    __half* P16  = Vt16 + (long long)G * SD;

    // ---- converts ----
    cvt32to16_k<<<dim3((int)((B_ * SD) / 1024)), 256, 0, stream>>>(hs, H16);
    wtrans_k<<<dim3(12, 12, 12), 256, 0, stream>>>(Wq, Wcat, LDL, 0);
    wtrans_k<<<dim3(12, 12, 12), 256, 0, stream>>>(Wk, Wcat, LDL, 768);
    wtrans_k<<<dim3(12, 12, 12), 256, 0, stream>>>(Wv, Wcat, LDL, 1536);
    bscat_k<<<dim3((L_ * 2304 + 255) / 256), 256, 0, stream>>>(bq, bk, bv, lk, lv, bsb, bss);

    const float scq = 0.036084391824351615f;   // 1/sqrt(768)
    float sig = 1.f;

    // ---- layers 1..11 (full) ----
    for (int lyr = 0; lyr < L_ - 1; ++lyr) {
        const __half* W = Wcat + (long long)lyr * LDL;
        const float* bb = bsb + lyr * 2304;
        const float* ss = bss + lyr * 2304;
        const float aQK = scq / (sig * sig);

        for (int b0 = 0; b0 < B_; b0 += G) {
            const int nb = (B_ - b0 < G) ? (B_ - b0) : G;
            const __half* hg = H16 + (long long)b0 * SD;

            gemm_qkv_k<<<dim3(18 * 8 * nb), 256, 0, stream>>>(
                hg, W, bb, ss, sig, Q16, K16, Vt16, 0, 18, nb);

            if ((nb & 7) == 0) {
                gemm_att_k<1, 1><<<dim3(nb * 64), 256, 0, stream>>>(
                    Q16, K16, aQK, P16, 768, 1024, SD, SD, SS, 8, 64, nb >> 3, rsp);
            } else {
                gemm_att_k<0, 1><<<dim3(8, 8, nb), 256, 0, stream>>>(
                    Q16, K16, aQK, P16, 768, 1024, SD, SD, SS, 8, 64, 1, rsp);
            }

            if ((nb & 7) == 0) {
                gemm_att_k<1, 2><<<dim3(nb * 48), 256, 0, stream>>>(
                    P16, Vt16, 4.f, H16 + (long long)b0 * SD, 1024, 768, SS, SD, SD,
                    6, 48, nb >> 3, rsp);
            } else {
                gemm_att_k<0, 2><<<dim3(6, 8, nb), 256, 0, stream>>>(
                    P16, Vt16, 4.f, H16 + (long long)b0 * SD, 1024, 768, SS, SD, SD,
                    6, 48, 1, rsp);
            }
        }
        sig *= 4.f;
    }

    // ---- layer 12: only row 0 of the output is needed ----
    const float aQK = scq / (sig * sig);
    q0_k<<<dim3(B_, 3), 256, 0, stream>>>(H16, Wcat, bq, q0f, sig);

    for (int b0 = 0; b0 < B_; b0 += G) {
        const int nb = (B_ - b0 < G) ? (B_ - b0) : G;
        const __half* hg = H16 + (long long)b0 * SD;

        // K,V projection only (cat rows 768..2303), region split at 768
        gemm_qkv_k<<<dim3(12 * 8 * nb), 256, 0, stream>>>(
            hg, Wcat + 11LL * LDL + 768LL * 768, bsb + 11 * 2304, bss + 11 * 2304,
            sig, K16 /*unused*/, K16, Vt16, 768, 12, nb);

        s0_k<<<dim3(nb, 4), 256, 0, stream>>>(q0f, K16, s0f, b0, aQK);
        sm0_k<<<dim3(nb), 256, 0, stream>>>(s0f, b0);
        o0_k<<<dim3(nb, 3), 256, 0, stream>>>(s0f, Vt16, o0f, b0, 1.f / sig);
    }

    headf_k<<<dim3(B_), 256, 0, stream>>>(o0f, Wh, bh, outp);
}